// Round 11
// baseline (420.013 us; speedup 1.0000x reference)
//
#include <hip/hip_runtime.h>

#define N_NODES_C 100000
#define N_EDGES_C 1200000
#define NUM_GRAPHS_C 64
#define D_C 64
#define CAP_C 64
#define NPASS_C 8
#define BN_EPS_C 1e-5f

typedef unsigned short u16;
typedef unsigned int u32;

using frag_ab = __attribute__((ext_vector_type(8))) short;  // 8 bf16 (4 VGPRs)
using f32x4   = __attribute__((ext_vector_type(4))) float;

__device__ __forceinline__ u16 f2bf(float f) {  // RTNE
    u32 x = __float_as_uint(f);
    x += 0x7fffu + ((x >> 16) & 1u);
    return (u16)(x >> 16);
}
__device__ __forceinline__ float bf2f(u16 u) {
    return __uint_as_float(((u32)u) << 16);
}

// ------------------- prep: x -> bf16, W1/W2 -> bf16 [n][k] ----------------
__global__ void k_prep(const float* __restrict__ x,
                       const float* __restrict__ W1, const float* __restrict__ W2,
                       u16* __restrict__ Xb, u16* __restrict__ Wb1,
                       u16* __restrict__ Wb2) {
    int i = blockIdx.x * 256 + threadIdx.x;
    int base = i * 4;
    if (base < N_NODES_C * D_C) {
        float4 f = *(const float4*)(x + base);
        ushort4 o;
        o.x = f2bf(f.x); o.y = f2bf(f.y); o.z = f2bf(f.z); o.w = f2bf(f.w);
        *(ushort4*)(Xb + base) = o;
    }
    if (i < 4096) {  // W[k][n] -> Wb[n][k]
        int n = i >> 6, k = i & 63;
        Wb1[i] = f2bf(W1[k * 64 + n]);
        Wb2[i] = f2bf(W2[k * 64 + n]);
    }
}

// ------------------- XCD-swizzled bucket scatter (R10-proven) -------------
__global__ void __launch_bounds__(256) k_scatter(
        const int* __restrict__ src, const int* __restrict__ dst,
        int* __restrict__ cnt, int* __restrict__ col) {
    int pass = blockIdx.x & (NPASS_C - 1);
    int chunk = blockIdx.x >> 3;
    int nchunks = gridDim.x >> 3;
    const int RANGE = N_NODES_C / NPASS_C;  // 12500
    int lo = pass * RANGE;
    int hi = (pass == NPASS_C - 1) ? N_NODES_C : lo + RANGE;
    const int nquads = N_EDGES_C / 4;  // 300000
    int tid = chunk * 256 + threadIdx.x;
    int nthreads = nchunks * 256;
    const int4* dst4 = (const int4*)dst;
    const int4* src4 = (const int4*)src;
    for (int i = tid; i < nquads; i += nthreads) {
        int4 d4 = dst4[i];
        int dd[4] = {d4.x, d4.y, d4.z, d4.w};
        bool in0 = dd[0] >= lo && dd[0] < hi;
        bool in1 = dd[1] >= lo && dd[1] < hi;
        bool in2 = dd[2] >= lo && dd[2] < hi;
        bool in3 = dd[3] >= lo && dd[3] < hi;
        if (in0 | in1 | in2 | in3) {
            int4 s4 = src4[i];
            int ss[4] = {s4.x, s4.y, s4.z, s4.w};
            bool in[4] = {in0, in1, in2, in3};
#pragma unroll
            for (int k = 0; k < 4; ++k) {
                if (in[k]) {
                    int pos = atomicAdd(&cnt[dd[k]], 1);
                    if (pos < CAP_C) col[(size_t)dd[k] * CAP_C + pos] = ss[k];
                }
            }
        }
    }
}

// ------------------- GEMM via MFMA 16x16x32 bf16 --------------------------
// Output T in SLICED layout Ts[f>>3][node][f&7] (gather needs per-XCD
// L2-resident 1.6 MB slices). A-operand: node-major (gemm1, Xb) or sliced
// (gemm2, Ab) — sliced IS the A-fragment shape: 8 contiguous k per lane.
template <bool A_SLICED>
__device__ __forceinline__ void gemm_body(
        const u16* __restrict__ Xa, const u16* __restrict__ Wb,
        const int* __restrict__ cnt, u16* __restrict__ T) {
    int lane = threadIdx.x & 63;
    int q = lane >> 4, ln = lane & 15;
    int wave = blockIdx.x * 4 + (threadIdx.x >> 6);
    int nwaves = gridDim.x * 4;
    frag_ab bfr[4][2];
#pragma unroll
    for (int nt = 0; nt < 4; ++nt)
#pragma unroll
        for (int kh = 0; kh < 2; ++kh)
            bfr[nt][kh] = *(const frag_ab*)(Wb + (nt * 16 + ln) * 64 + kh * 32 + q * 8);
    const int nstrips = N_NODES_C / 16;
    for (int s = wave; s < nstrips; s += nwaves) {
        int r0 = s * 16;
        frag_ab a0, a1;
        if (A_SLICED) {
            a0 = *(const frag_ab*)(Xa + ((size_t)q * N_NODES_C + r0 + ln) * 8);
            a1 = *(const frag_ab*)(Xa + ((size_t)(q + 4) * N_NODES_C + r0 + ln) * 8);
        } else {
            a0 = *(const frag_ab*)(Xa + (size_t)(r0 + ln) * 64 + q * 8);
            a1 = *(const frag_ab*)(Xa + (size_t)(r0 + ln) * 64 + 32 + q * 8);
        }
        f32x4 acc[4];
#pragma unroll
        for (int nt = 0; nt < 4; ++nt) {
            acc[nt] = (f32x4){0.f, 0.f, 0.f, 0.f};
            acc[nt] = __builtin_amdgcn_mfma_f32_16x16x32_bf16(a0, bfr[nt][0], acc[nt], 0, 0, 0);
            acc[nt] = __builtin_amdgcn_mfma_f32_16x16x32_bf16(a1, bfr[nt][1], acc[nt], 0, 0, 0);
        }
        float di[4];
#pragma unroll
        for (int reg = 0; reg < 4; ++reg)
            di[reg] = rsqrtf((float)(cnt[r0 + q * 4 + reg] + 1));
#pragma unroll
        for (int nt = 0; nt < 4; ++nt)
#pragma unroll
            for (int reg = 0; reg < 4; ++reg) {
                int n = nt * 16 + ln;
                int row = r0 + q * 4 + reg;
                T[((size_t)(n >> 3) * N_NODES_C + row) * 8 + (n & 7)] =
                    f2bf(acc[nt][reg] * di[reg]);
            }
    }
}

__global__ void __launch_bounds__(256) k_gemm1(
        const u16* __restrict__ Xb, const u16* __restrict__ Wb,
        const int* __restrict__ cnt, u16* __restrict__ T) {
    gemm_body<false>(Xb, Wb, cnt, T);
}
__global__ void __launch_bounds__(256) k_gemm2(
        const u16* __restrict__ Ab, const u16* __restrict__ Wb,
        const int* __restrict__ cnt, u16* __restrict__ T) {
    gemm_body<true>(Ab, Wb, cnt, T);
}

// ------------------- feature-sliced gather --------------------------------
// slice = blockIdx&7 -> XCD slice (R10-validated swizzle). Each XCD reads
// ONLY its 1.6 MB Ts slice -> edge reads are L2 hits instead of LLC misses
// (R5-R10 plateau: ~94 us latency-bound on random 128 B LLC rows).
// Lane = (edge-slot e in [0,16), feature-pair g in [0,4)): 16 edges per
// batch of 4 B loads; slot 0 = self row. shfl_xor(4,8,16,32) reduce;
// epilogue + store/pool on e==0 lanes. Contiguous node chunks per wave ->
// run-length pooling (~3 flushes/wave).
template <bool POOL>
__device__ __forceinline__ void gather_body(
        const u16* __restrict__ Ts, const int* __restrict__ col,
        const int* __restrict__ cnt,
        const float* __restrict__ b, const float* __restrict__ g,
        const float* __restrict__ be, const float* __restrict__ m,
        const float* __restrict__ v, const int* __restrict__ batch,
        u16* __restrict__ Ab, float* __restrict__ pooled) {
    int lane = threadIdx.x & 63;
    int e = lane >> 2;   // edge slot 0..15
    int gq = lane & 3;   // feature pair 0..3
    int slice = blockIdx.x & 7;
    int wave = (blockIdx.x >> 3) * 4 + (threadIdx.x >> 6);
    int nwaves = (gridDim.x >> 3) * 4;
    int f0 = slice * 8 + gq * 2;
    float sc0 = g[f0] * rsqrtf(v[f0] + BN_EPS_C);
    float c00 = (b[f0] - m[f0]) * sc0 + be[f0];
    float sc1 = g[f0 + 1] * rsqrtf(v[f0 + 1] + BN_EPS_C);
    float c01 = (b[f0 + 1] - m[f0 + 1]) * sc1 + be[f0 + 1];
    const u16* Tss = Ts + (size_t)slice * N_NODES_C * 8;
    u16* Abs = POOL ? nullptr : Ab + (size_t)slice * N_NODES_C * 8;
    const int chunk = (N_NODES_C + nwaves - 1) / nwaves;
    int r0 = wave * chunk;
    int r1 = r0 + chunk; if (r1 > N_NODES_C) r1 = N_NODES_C;
    float p0 = 0.f, p1 = 0.f; int curg = -1;
    for (int r = r0; r < r1; ++r) {
        int rr = __builtin_amdgcn_readfirstlane(r);
        int deg = cnt[rr]; if (deg > CAP_C) deg = CAP_C;
        int tot = deg + 1;  // slot 0 = self
        const int* cb = col + (size_t)rr * CAP_C;
        float a0 = 0.f, a1 = 0.f;
        for (int j = 0; j < tot; j += 16) {
            int slot = j + e;
            bool valid = slot < tot;
            int ci = cb[(valid && slot > 0) ? slot - 1 : 0];
            int idx = (slot == 0) ? rr : (valid ? ci : rr);
            u32 tv = *(const u32*)(Tss + (size_t)idx * 8 + gq * 2);
            a0 += valid ? __uint_as_float(tv << 16) : 0.f;
            a1 += valid ? __uint_as_float(tv & 0xffff0000u) : 0.f;
        }
#pragma unroll
        for (int off = 4; off <= 32; off <<= 1) {
            a0 += __shfl_xor(a0, off, 64);
            a1 += __shfl_xor(a1, off, 64);
        }
        float dr = rsqrtf((float)(deg + 1));
        float v0 = fmaxf(fmaf(a0 * dr, sc0, c00), 0.f);
        float v1 = fmaxf(fmaf(a1 * dr, sc1, c01), 0.f);
        if (POOL) {
            int gid = batch[rr];
            if (gid != curg) {
                if (curg >= 0 && e == 0) {
                    atomicAdd(&pooled[curg * 64 + f0], p0);
                    atomicAdd(&pooled[curg * 64 + f0 + 1], p1);
                }
                curg = gid; p0 = 0.f; p1 = 0.f;
            }
            p0 += v0; p1 += v1;
        } else if (e == 0) {
            u32 pk = (u32)f2bf(v0) | ((u32)f2bf(v1) << 16);
            *(u32*)(Abs + (size_t)rr * 8 + gq * 2) = pk;
        }
    }
    if (POOL && curg >= 0 && e == 0) {
        atomicAdd(&pooled[curg * 64 + f0], p0);
        atomicAdd(&pooled[curg * 64 + f0 + 1], p1);
    }
}

__global__ void __launch_bounds__(256) k_gather1(
        const u16* __restrict__ Ts, const int* __restrict__ col,
        const int* __restrict__ cnt,
        const float* __restrict__ b, const float* __restrict__ g,
        const float* __restrict__ be, const float* __restrict__ m,
        const float* __restrict__ v, u16* __restrict__ Ab) {
    gather_body<false>(Ts, col, cnt, b, g, be, m, v, nullptr, Ab, nullptr);
}

__global__ void __launch_bounds__(256) k_gather2(
        const u16* __restrict__ Ts, const int* __restrict__ col,
        const int* __restrict__ cnt,
        const float* __restrict__ b, const float* __restrict__ g,
        const float* __restrict__ be, const float* __restrict__ m,
        const float* __restrict__ v, const int* __restrict__ batch,
        float* __restrict__ pooled) {
    gather_body<true>(Ts, col, cnt, b, g, be, m, v, batch, nullptr, pooled);
}

// ----------------------------- classifier --------------------------------
__global__ void k_final(const float* __restrict__ pooled, const int* __restrict__ batch,
                        const float* __restrict__ Wc, const float* __restrict__ bc,
                        float* __restrict__ out) {
    __shared__ float sp[64 * 65];
    __shared__ int sub[64];
    int t = threadIdx.x;  // 256 threads
    for (int i = t; i < 4096; i += 256) sp[(i >> 6) * 65 + (i & 63)] = pooled[i];
    if (t < 64) {
        int lo = 0, hi = N_NODES_C;
        while (lo < hi) { int mid = (lo + hi) >> 1; if (batch[mid] > t) hi = mid; else lo = mid + 1; }
        sub[t] = lo;  // first index with batch > t
    }
    __syncthreads();
    if (t < 64) {
        int gi = t;
        int lb = gi ? sub[gi - 1] : 0;
        int cntg = sub[gi] - lb;
        float inv = 1.0f / fmaxf((float)cntg, 1.0f);
        float a0 = 0.f, a1 = 0.f;
#pragma unroll 8
        for (int f = 0; f < 64; ++f) {
            float p = sp[gi * 65 + f];
            a0 = fmaf(p, Wc[f * 2 + 0], a0);
            a1 = fmaf(p, Wc[f * 2 + 1], a1);
        }
        out[gi * 2 + 0] = a0 * inv + bc[0];
        out[gi * 2 + 1] = a1 * inv + bc[1];
    }
}

extern "C" void kernel_launch(void* const* d_in, const int* in_sizes, int n_in,
                              void* d_out, int out_size, void* d_ws, size_t ws_size,
                              hipStream_t stream) {
    const float* x    = (const float*)d_in[0];
    const int*   ei   = (const int*)d_in[1];
    const int*   batch= (const int*)d_in[2];
    const float* W1 = (const float*)d_in[3];
    const float* b1 = (const float*)d_in[4];
    const float* g1 = (const float*)d_in[5];
    const float* be1= (const float*)d_in[6];
    const float* m1 = (const float*)d_in[7];
    const float* v1 = (const float*)d_in[8];
    const float* W2 = (const float*)d_in[9];
    const float* b2 = (const float*)d_in[10];
    const float* g2 = (const float*)d_in[11];
    const float* be2= (const float*)d_in[12];
    const float* m2 = (const float*)d_in[13];
    const float* v2 = (const float*)d_in[14];
    const float* Wc = (const float*)d_in[15];
    const float* bc = (const float*)d_in[16];
    float* out = (float*)d_out;

    char* ws = (char*)d_ws;
    size_t off = 0;
    auto alloc = [&](size_t bytes) {
        size_t o = off;
        off = (off + bytes + 511) & ~(size_t)511;
        return o;
    };
    size_t o_cnt   = alloc((size_t)N_NODES_C * 4);
    size_t o_pool  = alloc((size_t)NUM_GRAPHS_C * D_C * 4);
    size_t zero_bytes = off;  // [cnt | pooled] zeroed each call
    size_t o_col   = alloc((size_t)N_NODES_C * CAP_C * 4 + 1024);  // buckets (+pad)
    size_t o_xb    = alloc((size_t)N_NODES_C * D_C * 2);
    size_t o_wb1   = alloc(4096 * 2);
    size_t o_wb2   = alloc(4096 * 2);
    size_t o_t     = alloc((size_t)N_NODES_C * D_C * 2);  // Ts sliced bf16
    size_t o_ab    = alloc((size_t)N_NODES_C * D_C * 2);  // Ab sliced bf16
    (void)ws_size; (void)in_sizes; (void)n_in; (void)out_size;

    int*   cnt    = (int*)(ws + o_cnt);
    float* pooled = (float*)(ws + o_pool);
    int*   col    = (int*)(ws + o_col);
    u16*   Xb     = (u16*)(ws + o_xb);
    u16*   Wb1    = (u16*)(ws + o_wb1);
    u16*   Wb2    = (u16*)(ws + o_wb2);
    u16*   T      = (u16*)(ws + o_t);
    u16*   Ab     = (u16*)(ws + o_ab);

    const int* srcp = ei;
    const int* dstp = ei + N_EDGES_C;

    hipMemsetAsync(ws, 0, zero_bytes, stream);

    int pblocks = (N_NODES_C * D_C / 4 + 255) / 256;  // 6250
    int sblocks = 2048;   // scatter: 256 chunks x 8 XCD ranges
    int gblocks = 2048;   // gather: 8 slices x 256 blocks (1024 waves/slice)
    int mblocks = 1563;   // gemm: 6252 waves, one 16-row strip each
    k_prep<<<pblocks, 256, 0, stream>>>(x, W1, W2, Xb, Wb1, Wb2);
    k_scatter<<<sblocks, 256, 0, stream>>>(srcp, dstp, cnt, col);

    k_gemm1<<<mblocks, 256, 0, stream>>>(Xb, Wb1, cnt, T);
    k_gather1<<<gblocks, 256, 0, stream>>>(T, col, cnt, b1, g1, be1, m1, v1, Ab);
    k_gemm2<<<mblocks, 256, 0, stream>>>(Ab, Wb2, cnt, T);
    k_gather2<<<gblocks, 256, 0, stream>>>(T, col, cnt, b2, g2, be2, m2, v2,
                                           batch, pooled);
    k_final<<<1, 256, 0, stream>>>(pooled, batch, Wc, bc, out);
}

// Round 12
// 376.266 us; speedup vs baseline: 1.1163x; 1.1163x over previous
//
#include <hip/hip_runtime.h>

#define N_NODES_C 100000
#define N_EDGES_C 1200000
#define NUM_GRAPHS_C 64
#define D_C 64
#define CAP_C 64
#define NPASS_C 8
#define BN_EPS_C 1e-5f

typedef unsigned short u16;
typedef unsigned int u32;

using frag_ab = __attribute__((ext_vector_type(8))) short;  // 8 bf16 (4 VGPRs)
using f32x4   = __attribute__((ext_vector_type(4))) float;

__device__ __forceinline__ u16 f2bf(float f) {  // RTNE
    u32 x = __float_as_uint(f);
    x += 0x7fffu + ((x >> 16) & 1u);
    return (u16)(x >> 16);
}
__device__ __forceinline__ float bf2f(u16 u) {
    return __uint_as_float(((u32)u) << 16);
}

// ------------------- prep: x -> bf16, W1/W2 -> bf16 [n][k] ----------------
__global__ void k_prep(const float* __restrict__ x,
                       const float* __restrict__ W1, const float* __restrict__ W2,
                       u16* __restrict__ Xb, u16* __restrict__ Wb1,
                       u16* __restrict__ Wb2) {
    int i = blockIdx.x * 256 + threadIdx.x;
    int base = i * 4;
    if (base < N_NODES_C * D_C) {
        float4 f = *(const float4*)(x + base);
        ushort4 o;
        o.x = f2bf(f.x); o.y = f2bf(f.y); o.z = f2bf(f.z); o.w = f2bf(f.w);
        *(ushort4*)(Xb + base) = o;
    }
    if (i < 4096) {  // W[k][n] -> Wb[n][k]
        int n = i >> 6, k = i & 63;
        Wb1[i] = f2bf(W1[k * 64 + n]);
        Wb2[i] = f2bf(W2[k * 64 + n]);
    }
}

// ------------------- XCD-swizzled bucket scatter (R10-proven) -------------
__global__ void __launch_bounds__(256) k_scatter(
        const int* __restrict__ src, const int* __restrict__ dst,
        int* __restrict__ cnt, int* __restrict__ col) {
    int pass = blockIdx.x & (NPASS_C - 1);
    int chunk = blockIdx.x >> 3;
    int nchunks = gridDim.x >> 3;
    const int RANGE = N_NODES_C / NPASS_C;  // 12500
    int lo = pass * RANGE;
    int hi = (pass == NPASS_C - 1) ? N_NODES_C : lo + RANGE;
    const int nquads = N_EDGES_C / 4;  // 300000
    int tid = chunk * 256 + threadIdx.x;
    int nthreads = nchunks * 256;
    const int4* dst4 = (const int4*)dst;
    const int4* src4 = (const int4*)src;
    for (int i = tid; i < nquads; i += nthreads) {
        int4 d4 = dst4[i];
        int dd[4] = {d4.x, d4.y, d4.z, d4.w};
        bool in0 = dd[0] >= lo && dd[0] < hi;
        bool in1 = dd[1] >= lo && dd[1] < hi;
        bool in2 = dd[2] >= lo && dd[2] < hi;
        bool in3 = dd[3] >= lo && dd[3] < hi;
        if (in0 | in1 | in2 | in3) {
            int4 s4 = src4[i];
            int ss[4] = {s4.x, s4.y, s4.z, s4.w};
            bool in[4] = {in0, in1, in2, in3};
#pragma unroll
            for (int k = 0; k < 4; ++k) {
                if (in[k]) {
                    int pos = atomicAdd(&cnt[dd[k]], 1);
                    if (pos < CAP_C) col[(size_t)dd[k] * CAP_C + pos] = ss[k];
                }
            }
        }
    }
}

// ------------------- GEMM via MFMA 16x16x32 bf16 (R11-verified) -----------
// Output T in SLICED layout Ts[f>>3][node][f&7]. A: node-major (gemm1) or
// sliced (gemm2 — sliced IS the A-fragment shape: 8 contiguous k per lane).
template <bool A_SLICED>
__device__ __forceinline__ void gemm_body(
        const u16* __restrict__ Xa, const u16* __restrict__ Wb,
        const int* __restrict__ cnt, u16* __restrict__ T) {
    int lane = threadIdx.x & 63;
    int q = lane >> 4, ln = lane & 15;
    int wave = blockIdx.x * 4 + (threadIdx.x >> 6);
    int nwaves = gridDim.x * 4;
    frag_ab bfr[4][2];
#pragma unroll
    for (int nt = 0; nt < 4; ++nt)
#pragma unroll
        for (int kh = 0; kh < 2; ++kh)
            bfr[nt][kh] = *(const frag_ab*)(Wb + (nt * 16 + ln) * 64 + kh * 32 + q * 8);
    const int nstrips = N_NODES_C / 16;
    for (int s = wave; s < nstrips; s += nwaves) {
        int r0 = s * 16;
        frag_ab a0, a1;
        if (A_SLICED) {
            a0 = *(const frag_ab*)(Xa + ((size_t)q * N_NODES_C + r0 + ln) * 8);
            a1 = *(const frag_ab*)(Xa + ((size_t)(q + 4) * N_NODES_C + r0 + ln) * 8);
        } else {
            a0 = *(const frag_ab*)(Xa + (size_t)(r0 + ln) * 64 + q * 8);
            a1 = *(const frag_ab*)(Xa + (size_t)(r0 + ln) * 64 + 32 + q * 8);
        }
        f32x4 acc[4];
#pragma unroll
        for (int nt = 0; nt < 4; ++nt) {
            acc[nt] = (f32x4){0.f, 0.f, 0.f, 0.f};
            acc[nt] = __builtin_amdgcn_mfma_f32_16x16x32_bf16(a0, bfr[nt][0], acc[nt], 0, 0, 0);
            acc[nt] = __builtin_amdgcn_mfma_f32_16x16x32_bf16(a1, bfr[nt][1], acc[nt], 0, 0, 0);
        }
        float di[4];
#pragma unroll
        for (int reg = 0; reg < 4; ++reg)
            di[reg] = rsqrtf((float)(cnt[r0 + q * 4 + reg] + 1));
#pragma unroll
        for (int nt = 0; nt < 4; ++nt)
#pragma unroll
            for (int reg = 0; reg < 4; ++reg) {
                int n = nt * 16 + ln;
                int row = r0 + q * 4 + reg;
                T[((size_t)(n >> 3) * N_NODES_C + row) * 8 + (n & 7)] =
                    f2bf(acc[nt][reg] * di[reg]);
            }
    }
}

__global__ void __launch_bounds__(256) k_gemm1(
        const u16* __restrict__ Xb, const u16* __restrict__ Wb,
        const int* __restrict__ cnt, u16* __restrict__ T) {
    gemm_body<false>(Xb, Wb, cnt, T);
}
__global__ void __launch_bounds__(256) k_gemm2(
        const u16* __restrict__ Ab, const u16* __restrict__ Wb,
        const int* __restrict__ cnt, u16* __restrict__ T) {
    gemm_body<true>(Ab, Wb, cnt, T);
}

// ------------------- sliced gather, group-per-node, NO shuffle ------------
// slice = blockIdx&7 -> XCD (R10/R11-validated). Each XCD touches only its
// 1.6 MB Ts slice -> T reads are L2 hits (R11 FETCH decomposition: ~87%
// hit). R11's failure was instruction overhead (8 shfl + epilogue per
// node-slice); here wave = 8 groups x 8 features: each 8-lane group owns a
// CONTIGUOUS node chunk, lane = feature -> accumulator is complete per
// lane, zero shuffles, store = 16 B/group. col read: int4 per 4 edges,
// 8 lanes same addr. Run-length pooling per group (~1 flush).
template <bool POOL>
__device__ __forceinline__ void gather_body(
        const u16* __restrict__ Ts, const int* __restrict__ col,
        const int* __restrict__ cnt,
        const float* __restrict__ b, const float* __restrict__ g,
        const float* __restrict__ be, const float* __restrict__ m,
        const float* __restrict__ v, const int* __restrict__ batch,
        u16* __restrict__ Ab, float* __restrict__ pooled) {
    int lane = threadIdx.x & 63;
    int grp = lane >> 3;  // group 0..7 (one node at a time)
    int f   = lane & 7;   // feature within slice
    int slice = blockIdx.x & 7;
    int wave = (blockIdx.x >> 3) * 4 + (threadIdx.x >> 6);
    int nwaves = (gridDim.x >> 3) * 4;
    int gid = wave * 8 + grp;
    int ngroups = nwaves * 8;
    const int chunk = (N_NODES_C + ngroups - 1) / ngroups;
    int r0 = gid * chunk;
    int r1 = r0 + chunk; if (r1 > N_NODES_C) r1 = N_NODES_C;
    int f0 = slice * 8 + f;
    float sc = g[f0] * rsqrtf(v[f0] + BN_EPS_C);
    float c0 = (b[f0] - m[f0]) * sc + be[f0];
    const u16* Tss = Ts + (size_t)slice * N_NODES_C * 8;
    u16* Abs = POOL ? nullptr : Ab + (size_t)slice * N_NODES_C * 8;
    float psum = 0.f; int curg = -1;
    for (int r = r0; r < r1; ++r) {
        int deg = cnt[r]; if (deg > CAP_C) deg = CAP_C;
        const int* cb = col + (size_t)r * CAP_C;
        float acc = bf2f(Tss[(size_t)r * 8 + f]);  // self (dinv folded in T)
        for (int j = 0; j < deg; j += 4) {
            int4 c4 = *(const int4*)(cb + j);  // always in-bounds (CAP=64)
            int i0 = (j + 0 < deg) ? c4.x : r;
            int i1 = (j + 1 < deg) ? c4.y : r;
            int i2 = (j + 2 < deg) ? c4.z : r;
            int i3 = (j + 3 < deg) ? c4.w : r;
            u16 t0 = Tss[(size_t)i0 * 8 + f];
            u16 t1 = Tss[(size_t)i1 * 8 + f];
            u16 t2 = Tss[(size_t)i2 * 8 + f];
            u16 t3 = Tss[(size_t)i3 * 8 + f];
            acc += (j + 0 < deg) ? bf2f(t0) : 0.f;
            acc += (j + 1 < deg) ? bf2f(t1) : 0.f;
            acc += (j + 2 < deg) ? bf2f(t2) : 0.f;
            acc += (j + 3 < deg) ? bf2f(t3) : 0.f;
        }
        float dr = rsqrtf((float)(deg + 1));
        float val = fmaxf(fmaf(acc * dr, sc, c0), 0.f);
        if (POOL) {
            int gidb = batch[r];
            if (gidb != curg) {
                if (curg >= 0) atomicAdd(&pooled[curg * 64 + f0], psum);
                curg = gidb; psum = 0.f;
            }
            psum += val;
        } else {
            Abs[(size_t)r * 8 + f] = f2bf(val);  // 16 B per group
        }
    }
    if (POOL && curg >= 0) atomicAdd(&pooled[curg * 64 + f0], psum);
}

__global__ void __launch_bounds__(256) k_gather1(
        const u16* __restrict__ Ts, const int* __restrict__ col,
        const int* __restrict__ cnt,
        const float* __restrict__ b, const float* __restrict__ g,
        const float* __restrict__ be, const float* __restrict__ m,
        const float* __restrict__ v, u16* __restrict__ Ab) {
    gather_body<false>(Ts, col, cnt, b, g, be, m, v, nullptr, Ab, nullptr);
}

__global__ void __launch_bounds__(256) k_gather2(
        const u16* __restrict__ Ts, const int* __restrict__ col,
        const int* __restrict__ cnt,
        const float* __restrict__ b, const float* __restrict__ g,
        const float* __restrict__ be, const float* __restrict__ m,
        const float* __restrict__ v, const int* __restrict__ batch,
        float* __restrict__ pooled) {
    gather_body<true>(Ts, col, cnt, b, g, be, m, v, batch, nullptr, pooled);
}

// ----------------------------- classifier --------------------------------
__global__ void k_final(const float* __restrict__ pooled, const int* __restrict__ batch,
                        const float* __restrict__ Wc, const float* __restrict__ bc,
                        float* __restrict__ out) {
    __shared__ float sp[64 * 65];
    __shared__ int sub[64];
    int t = threadIdx.x;  // 256 threads
    for (int i = t; i < 4096; i += 256) sp[(i >> 6) * 65 + (i & 63)] = pooled[i];
    if (t < 64) {
        int lo = 0, hi = N_NODES_C;
        while (lo < hi) { int mid = (lo + hi) >> 1; if (batch[mid] > t) hi = mid; else lo = mid + 1; }
        sub[t] = lo;  // first index with batch > t
    }
    __syncthreads();
    if (t < 64) {
        int gi = t;
        int lb = gi ? sub[gi - 1] : 0;
        int cntg = sub[gi] - lb;
        float inv = 1.0f / fmaxf((float)cntg, 1.0f);
        float a0 = 0.f, a1 = 0.f;
#pragma unroll 8
        for (int f = 0; f < 64; ++f) {
            float p = sp[gi * 65 + f];
            a0 = fmaf(p, Wc[f * 2 + 0], a0);
            a1 = fmaf(p, Wc[f * 2 + 1], a1);
        }
        out[gi * 2 + 0] = a0 * inv + bc[0];
        out[gi * 2 + 1] = a1 * inv + bc[1];
    }
}

extern "C" void kernel_launch(void* const* d_in, const int* in_sizes, int n_in,
                              void* d_out, int out_size, void* d_ws, size_t ws_size,
                              hipStream_t stream) {
    const float* x    = (const float*)d_in[0];
    const int*   ei   = (const int*)d_in[1];
    const int*   batch= (const int*)d_in[2];
    const float* W1 = (const float*)d_in[3];
    const float* b1 = (const float*)d_in[4];
    const float* g1 = (const float*)d_in[5];
    const float* be1= (const float*)d_in[6];
    const float* m1 = (const float*)d_in[7];
    const float* v1 = (const float*)d_in[8];
    const float* W2 = (const float*)d_in[9];
    const float* b2 = (const float*)d_in[10];
    const float* g2 = (const float*)d_in[11];
    const float* be2= (const float*)d_in[12];
    const float* m2 = (const float*)d_in[13];
    const float* v2 = (const float*)d_in[14];
    const float* Wc = (const float*)d_in[15];
    const float* bc = (const float*)d_in[16];
    float* out = (float*)d_out;

    char* ws = (char*)d_ws;
    size_t off = 0;
    auto alloc = [&](size_t bytes) {
        size_t o = off;
        off = (off + bytes + 511) & ~(size_t)511;
        return o;
    };
    size_t o_cnt   = alloc((size_t)N_NODES_C * 4);
    size_t o_pool  = alloc((size_t)NUM_GRAPHS_C * D_C * 4);
    size_t zero_bytes = off;  // [cnt | pooled] zeroed each call
    size_t o_col   = alloc((size_t)N_NODES_C * CAP_C * 4 + 1024);  // buckets (+pad)
    size_t o_xb    = alloc((size_t)N_NODES_C * D_C * 2);
    size_t o_wb1   = alloc(4096 * 2);
    size_t o_wb2   = alloc(4096 * 2);
    size_t o_t     = alloc((size_t)N_NODES_C * D_C * 2);  // Ts sliced bf16
    size_t o_ab    = alloc((size_t)N_NODES_C * D_C * 2);  // Ab sliced bf16
    (void)ws_size; (void)in_sizes; (void)n_in; (void)out_size;

    int*   cnt    = (int*)(ws + o_cnt);
    float* pooled = (float*)(ws + o_pool);
    int*   col    = (int*)(ws + o_col);
    u16*   Xb     = (u16*)(ws + o_xb);
    u16*   Wb1    = (u16*)(ws + o_wb1);
    u16*   Wb2    = (u16*)(ws + o_wb2);
    u16*   T      = (u16*)(ws + o_t);
    u16*   Ab     = (u16*)(ws + o_ab);

    const int* srcp = ei;
    const int* dstp = ei + N_EDGES_C;

    hipMemsetAsync(ws, 0, zero_bytes, stream);

    int pblocks = (N_NODES_C * D_C / 4 + 255) / 256;  // 6250
    int sblocks = 2048;   // scatter: 256 chunks x 8 XCD ranges
    int gblocks = 1024;   // gather: 8 slices x 128 blocks = 4096 groups/slice
    int mblocks = 1563;   // gemm: 6252 waves, one 16-row strip each
    k_prep<<<pblocks, 256, 0, stream>>>(x, W1, W2, Xb, Wb1, Wb2);
    k_scatter<<<sblocks, 256, 0, stream>>>(srcp, dstp, cnt, col);

    k_gemm1<<<mblocks, 256, 0, stream>>>(Xb, Wb1, cnt, T);
    k_gather1<<<gblocks, 256, 0, stream>>>(T, col, cnt, b1, g1, be1, m1, v1, Ab);
    k_gemm2<<<mblocks, 256, 0, stream>>>(Ab, Wb2, cnt, T);
    k_gather2<<<gblocks, 256, 0, stream>>>(T, col, cnt, b2, g2, be2, m2, v2,
                                           batch, pooled);
    k_final<<<1, 256, 0, stream>>>(pooled, batch, Wc, bc, out);
}